// Round 11
// baseline (274.082 us; speedup 1.0000x reference)
//
#include <hip/hip_runtime.h>
#include <stdint.h>

#define BATCH 256
#define T_PREVN 128
#define T_CURN 129
#define N_COV 30
#define N_TREAT 57
#define N_CONF 5
#define HID 128
#define D_IN 87
#define D_CELL 92
#define GATES 512            // 4*H
#define PRED_N (T_CURN*BATCH)        // 33024
#define CONF_OFF (PRED_N*N_TREAT)    // 1882368

// ws layout
#define OFF_W1   0
#define SZ_W1    (57*8*2*64*8*2)             // 933888 B  W1 f16 B-frags
#define OFF_WIH  SZ_W1                        // 933888
#define SZ_WIH   (32*3*64*8*2)                // 98304 B  W_ih f16 B-frags
#define OFF_GX   (OFF_W1 + SZ_W1 + SZ_WIH)    // 1032192
#define SZ_GX    (PRED_N*512*2)               // 33816576 B  Gx f16
#define OFF_MT   (OFF_GX + SZ_GX)             // 34848768
#define SZ_MT    (PRED_N*40*2)                // 2641920 B  mT f16
#define WS_GX    (OFF_MT + SZ_MT)             // 37490688
// new: MFMA-scan weight fragments
#define OFF_WEFF WS_GX                         // 37490688
#define SZ_WEFF  (32*4*64*8*2)                 // 131072 B  W_eff A-frags (row'=u*4+gi)
#define OFF_WZF  (OFF_WEFF + SZ_WEFF)          // 37621760
#define SZ_WZF   (4*64*8*2)                    // 4096 B    W_z A-frags
#define WS_MF    (OFF_WZF + SZ_WZF)            // 37625856
// legacy gates
#define WS_NEED  SZ_W1
#define WS_NEED2 (SZ_W1 + SZ_MT)

typedef _Float16 h2 __attribute__((ext_vector_type(2)));
typedef _Float16 h4 __attribute__((ext_vector_type(4)));
typedef _Float16 h8 __attribute__((ext_vector_type(8)));
typedef float f32x4 __attribute__((ext_vector_type(4)));

__device__ inline float rcp_fast(float x){
#if __has_builtin(__builtin_amdgcn_rcpf)
    return __builtin_amdgcn_rcpf(x);
#else
    return 1.0f / x;
#endif
}
__device__ inline float sigmoid_f(float x){ return rcp_fast(1.0f + __expf(-x)); }
__device__ inline float tanh_f(float x){ return 1.0f - 2.0f*rcp_fast(1.0f + __expf(2.0f*x)); }

__device__ inline float dot2f(h2 a, h2 b, float c){
#if __has_builtin(__builtin_amdgcn_fdot2)
    return __builtin_amdgcn_fdot2(a, b, c, false);
#else
    return c + (float)a.x*(float)b.x + (float)a.y*(float)b.y;
#endif
}
__device__ inline unsigned short f2us(float v){
    _Float16 h = (_Float16)v;
    return __builtin_bit_cast(unsigned short, h);
}
__device__ inline h2 us2h2(unsigned int u){
    return __builtin_bit_cast(h2, u);
}

// ================= fused prep: W1 + W_ih frags + mT cov + W_eff/W_z frags ========
__global__ __launch_bounds__(256) void prep_all(
    const float* __restrict__ dW1, const float* __restrict__ W_ih,
    const float* __restrict__ cc, const float* __restrict__ W_hh,
    const float* __restrict__ W_z,
    _Float16* __restrict__ wsh, _Float16* __restrict__ wihf,
    _Float16* __restrict__ mT, _Float16* __restrict__ weff,
    _Float16* __restrict__ wzfr)
{
    const int bid = blockIdx.x;
    if (bid < 228){
        const int tid = bid*256 + threadIdx.x;
        const int treat = tid >> 10;
        const int r     = tid & 1023;
        const int ft    = r >> 7;
        const int ks    = (r >> 6) & 1;
        const int l     = r & 63;
        const int col   = ft*16 + (l & 15);
        const int kb    = ks*32 + ((l >> 4) << 3);
        h8 v;
        #pragma unroll
        for (int j = 0; j < 8; j++){
            const int k = kb + j;
            v[j] = (k < 35) ? (_Float16)dW1[(treat*35 + k)*128 + col] : (_Float16)0.0f;
        }
        *(h8*)(wsh + (size_t)tid*8) = v;
    } else if (bid < 252){
        const int tid = (bid - 228)*256 + threadIdx.x;
        const int ct  = tid / 192;
        const int rem = tid - ct*192;
        const int ks  = rem >> 6;
        const int l   = rem & 63;
        const int gate = ct*16 + (l & 15);
        const int kb   = ks*32 + ((l >> 4) << 3);
        h8 v;
        #pragma unroll
        for (int j = 0; j < 8; j++){
            const int k = kb + j;
            v[j] = (k < D_IN) ? (_Float16)W_ih[gate*D_CELL + k] : (_Float16)0.0f;
        }
        *(h8*)(wihf + (size_t)tid*8) = v;
    } else if (bid < 897){
        const int idx = (bid - 252)*256 + threadIdx.x;   // 645*256 == 33024*5
        const int n   = idx / 5;
        const int oct = idx - n*5;
        const int b = n & 255;
        const int t = n >> 8;
        const float* crow = cc + ((size_t)b*T_CURN + t)*N_COV;
        h8 v;
        #pragma unroll
        for (int j = 0; j < 8; j++){
            const int cj = oct*8 + j;
            v[j] = (cj >= 5 && cj < 35) ? (_Float16)crow[cj - 5] : (_Float16)0.0f;
        }
        *(h8*)(mT + (size_t)n*40 + oct*8) = v;
    } else if (bid < 929){
        // W_eff A-frags, gate rows reordered row' = u*4+gi.
        // frag-lane idx: mk = m*4+ks, lane l; value j: k = ks*32+(l>>4)*8+j
        const int idx = (bid - 897)*256 + threadIdx.x;   // 0..8191
        const int mk  = idx >> 6;
        const int l   = idx & 63;
        const int m   = mk >> 2;
        const int ks  = mk & 3;
        const int rowp = m*16 + (l & 15);
        const int u   = rowp >> 2;
        const int gi  = rowp & 3;
        const int g   = gi*128 + u;
        const int kb  = ks*32 + ((l >> 4) << 3);
        float wz[5];
        #pragma unroll
        for (int z = 0; z < 5; z++) wz[z] = W_ih[g*D_CELL + D_IN + z];
        h8 v;
        #pragma unroll
        for (int j = 0; j < 8; j++){
            const int k = kb + j;
            float f = W_hh[g*HID + k];
            #pragma unroll
            for (int z = 0; z < 5; z++) f += wz[z]*W_z[z*HID + k];
            v[j] = (_Float16)f;
        }
        *(h8*)(weff + (size_t)idx*8) = v;
    } else {
        // W_z A-frags (rows 0..4 valid, 5..15 zero)
        const int t2 = threadIdx.x;      // 0..255
        const int ks = t2 >> 6;
        const int l  = t2 & 63;
        const int row = l & 15;
        const int kb  = ks*32 + ((l >> 4) << 3);
        h8 v;
        #pragma unroll
        for (int j = 0; j < 8; j++)
            v[j] = (row < 5) ? (_Float16)W_z[row*HID + kb + j] : (_Float16)0.0f;
        *(h8*)(wzfr + (size_t)t2*8) = v;
    }
}

// ================= Gx GEMM (+ optional bias/d0 fold) ==============================
__global__ __launch_bounds__(256, 2) void gx_gemm(
    const float* __restrict__ pc, const float* __restrict__ pt,
    const float* __restrict__ init_input,
    const _Float16* __restrict__ wihf, _Float16* __restrict__ Gx,
    const float* __restrict__ W_ih, const float* __restrict__ W_z,
    const float* __restrict__ b_ih, const float* __restrict__ b_hh,
    const float* __restrict__ b_z, const float* __restrict__ h0,
    const float* __restrict__ z0, const int fold_bias)
{
    __shared__ alignas(16) _Float16 a_lds[64*104];
    __shared__ alignas(16) _Float16 gx_lds[64*264];
    __shared__ float be_lds[512];
    __shared__ float d0_lds[512];
    __shared__ float z0c[5];

    const int tid = threadIdx.x;
    const int nb  = blockIdx.x * 64;

    for (int idx = tid; idx < 64*96; idx += 256){
        const int r = idx / 96;
        const int k = idx - r*96;
        const int n = nb + r;
        const int bb = n / 129;
        const int t  = n - bb*129;
        float v = 0.0f;
        if (k < D_IN){
            if (t == 0) v = init_input[k];
            else        v = (k < N_COV) ? pc[(bb*T_PREVN + t-1)*N_COV + k]
                                        : pt[(bb*T_PREVN + t-1)*N_TREAT + (k - N_COV)];
        }
        a_lds[r*104 + k] = (_Float16)v;
    }
    if (fold_bias && tid < 5){
        float a0 = 0.f, a1 = 0.f;
        #pragma unroll 8
        for (int k = 0; k < HID; k += 2){
            a0 += W_z[tid*HID + k]     * h0[k];
            a1 += W_z[tid*HID + k + 1] * h0[k + 1];
        }
        z0c[tid] = z0[tid] - b_z[tid] - (a0 + a1);
    }
    __syncthreads();
    if (fold_bias){
        for (int g = tid; g < 512; g += 256){
            float w0v = W_ih[g*D_CELL + D_IN + 0];
            float w1v = W_ih[g*D_CELL + D_IN + 1];
            float w2v = W_ih[g*D_CELL + D_IN + 2];
            float w3v = W_ih[g*D_CELL + D_IN + 3];
            float w4v = W_ih[g*D_CELL + D_IN + 4];
            be_lds[g] = b_ih[g] + b_hh[g]
                      + w0v*b_z[0] + w1v*b_z[1] + w2v*b_z[2] + w3v*b_z[3] + w4v*b_z[4];
            d0_lds[g] = w0v*z0c[0] + w1v*z0c[1] + w2v*z0c[2] + w3v*z0c[3] + w4v*z0c[4];
        }
        __syncthreads();
    }

    const int w    = tid >> 6;
    const int l    = tid & 63;
    const int col  = l & 15;
    const int quad = l >> 4;

    const _Float16* ar = a_lds + (w*16 + col)*104 + quad*8;
    const h8 a0 = *(const h8*)(ar);
    const h8 a1 = *(const h8*)(ar + 32);
    const h8 a2 = *(const h8*)(ar + 64);

    for (int half = 0; half < 2; half++){
        #pragma unroll
        for (int ct8 = 0; ct8 < 16; ct8++){
            const int ct = half*16 + ct8;
            const _Float16* bp = wihf + (size_t)ct*1536 + l*8;
            const h8 b0 = *(const h8*)(bp);
            const h8 b1 = *(const h8*)(bp + 512);
            const h8 b2 = *(const h8*)(bp + 1024);
            f32x4 acc = {0.f, 0.f, 0.f, 0.f};
            acc = __builtin_amdgcn_mfma_f32_16x16x32_f16(a0, b0, acc, 0, 0, 0);
            acc = __builtin_amdgcn_mfma_f32_16x16x32_f16(a1, b1, acc, 0, 0, 0);
            acc = __builtin_amdgcn_mfma_f32_16x16x32_f16(a2, b2, acc, 0, 0, 0);
            #pragma unroll
            for (int r4 = 0; r4 < 4; r4++){
                float val = acc[r4];
                if (fold_bias){
                    const int g = ct*16 + col;
                    const int n = nb + w*16 + quad*4 + r4;
                    val += be_lds[g];
                    if (n % 129 == 0) val += d0_lds[g];
                }
                gx_lds[(w*16 + quad*4 + r4)*264 + ct8*16 + col] = (_Float16)val;
            }
        }
        __syncthreads();
        #pragma unroll
        for (int it = 0; it < 8; it++){
            const int idx = it*256 + tid;
            const int r   = idx >> 5;
            const int seg = idx & 31;
            *(h8*)(Gx + ((size_t)(nb + r))*512 + half*256 + seg*8) =
                *(const h8*)(&gx_lds[r*264 + seg*8]);
        }
        __syncthreads();
    }
}

// ================= MFMA scan: 16 blocks x 16 batches, 1 barrier/step ==============
// gates[512x16] = W_eff @ H via 8 MFMA/wave/step (tiles m0=w, m1=w+16).
// W_eff rows reordered row'=u*4+gi so lane (col=batch,l>>4) holds the 4 gates of
// unit u=4m+(l>>4) in acc regs 0..3 -> activation fully in-lane, c in-register.
// h round-trips via XOR-swizzled LDS [batch][128] (group^=batch&7 -> 2-way banks,
// 16B-aligned b128). Bias folded into Gx by gx_gemm. z = W_z@H on wave15 (1-step
// pipelined, LDS-buffered, written out once). Gx: 3-buffer 2-deep prefetch.
__global__ __launch_bounds__(1024, 4) void lstm_scan_mfma(
    const float* __restrict__ h0, const float* __restrict__ c0,
    const float* __restrict__ b_z,
    const _Float16* __restrict__ weff, const _Float16* __restrict__ wzfr,
    const _Float16* __restrict__ Gx,
    float* __restrict__ zs_out, _Float16* __restrict__ mT)
{
    const int tid = threadIdx.x;
    const int w   = tid >> 6;        // wave = Gx batch-row loader
    const int l   = tid & 63;
    const int col = l & 15;          // batch within tile
    const int q   = l >> 4;
    const int b0  = blockIdx.x * 16;

    __shared__ alignas(16) _Float16 hsw[2][16*128];     // 8192 B, swizzled
    __shared__ alignas(16) _Float16 gxc[3][16*520];     // 49920 B
    __shared__ float zl[129*80];                         // 41280 B

    // h0 -> hsw[0] (broadcast over 16 batch cols, swizzled)
    for (int idx = tid; idx < 2048; idx += 1024){
        const int bt = idx >> 7;
        const int u  = idx & 127;
        const int gp = (u >> 3) ^ (bt & 7);
        hsw[0][bt*128 + gp*8 + (u & 7)] = (_Float16)h0[u];
    }
    // Gx row t=0 -> gxc[0]; preA = row t=1
    {
        const uint4 p = *(const uint4*)(Gx + ((size_t)(b0 + w)*T_CURN + 0)*512 + (size_t)l*8);
        *(uint4*)(&gxc[0][w*520 + l*8]) = p;
    }
    uint4 preA = *(const uint4*)(Gx + ((size_t)(b0 + w)*T_CURN + 1)*512 + (size_t)l*8);

    // A-frags
    h8 aw0[4], aw1[4], az[4];
    #pragma unroll
    for (int ks = 0; ks < 4; ks++){
        aw0[ks] = *(const h8*)(weff + (size_t)((w*4 + ks)*64 + l)*8);
        aw1[ks] = *(const h8*)(weff + (size_t)(((w + 16)*4 + ks)*64 + l)*8);
        az[ks]  = *(const h8*)(wzfr + (size_t)(ks*64 + l)*8);
    }
    const int u0 = 4*w + q;
    const int u1 = 64 + 4*w + q;
    float cr0 = c0[u0];
    float cr1 = c0[u1];
    __syncthreads();

    for (int t = 0; t < T_CURN; t++){
        const int cur  = t & 1;
        const int g3   = t % 3;
        uint4 preB;
        const bool ldB = (t + 2 <= 128);
        if (ldB)
            preB = *(const uint4*)(Gx + ((size_t)(b0 + w)*T_CURN + (t + 2))*512 + (size_t)l*8);

        // MFMA: gates (2 tiles) + z (wave15), shared B-frags (h_{t-1})
        f32x4 acc0 = {0.f,0.f,0.f,0.f};
        f32x4 acc1 = {0.f,0.f,0.f,0.f};
        f32x4 accz = {0.f,0.f,0.f,0.f};
        #pragma unroll
        for (int ks = 0; ks < 4; ks++){
            const int gp = (ks*4 + q) ^ (col & 7);
            const h8 hb = *(const h8*)(&hsw[cur][col*128 + gp*8]);
            acc0 = __builtin_amdgcn_mfma_f32_16x16x32_f16(aw0[ks], hb, acc0, 0, 0, 0);
            acc1 = __builtin_amdgcn_mfma_f32_16x16x32_f16(aw1[ks], hb, acc1, 0, 0, 0);
            if (w == 15)
                accz = __builtin_amdgcn_mfma_f32_16x16x32_f16(az[ks], hb, accz, 0, 0, 0);
        }

        // gates += Gx (bias already folded in)
        float g0[4], g1[4];
        #pragma unroll
        for (int r = 0; r < 4; r++){
            g0[r] = acc0[r] + (float)gxc[g3][col*520 + r*128 + u0];
            g1[r] = acc1[r] + (float)gxc[g3][col*520 + r*128 + u1];
        }
        // activation, in-lane (gi order: 0=i 1=f 2=g 3=o)
        float hv0, hv1;
        {
            const float i_ = sigmoid_f(g0[0]);
            const float f_ = sigmoid_f(g0[1]);
            const float t_ = tanh_f(g0[2]);
            const float o_ = sigmoid_f(g0[3]);
            cr0 = f_*cr0 + i_*t_;
            hv0 = o_ * tanh_f(cr0);
        }
        {
            const float i_ = sigmoid_f(g1[0]);
            const float f_ = sigmoid_f(g1[1]);
            const float t_ = tanh_f(g1[2]);
            const float o_ = sigmoid_f(g1[3]);
            cr1 = f_*cr1 + i_*t_;
            hv1 = o_ * tanh_f(cr1);
        }
        // write h (swizzled)
        {
            const int gp0 = (u0 >> 3) ^ (col & 7);
            hsw[cur ^ 1][col*128 + gp0*8 + (u0 & 7)] = (_Float16)hv0;
            const int gp1 = (u1 >> 3) ^ (col & 7);
            hsw[cur ^ 1][col*128 + gp1*8 + (u1 & 7)] = (_Float16)hv1;
        }
        // z_{t-1} (wave15; acc row = q*4+r = zi, col = batch)
        if (w == 15 && t > 0){
            #pragma unroll
            for (int r = 0; r < 4; r++){
                const int zi = q*4 + r;
                if (zi < 5) zl[(t - 1)*80 + zi*16 + col] = accz[r];
            }
        }
        // commit Gx row t+1, shift prefetch pipe
        if (t + 1 <= 128)
            *(uint4*)(&gxc[(t + 1) % 3][w*520 + l*8]) = preA;
        if (ldB) preA = preB;
        __syncthreads();
    }

    // z_128 from H_128 (in hsw[1])
    if (w == 15){
        f32x4 accz = {0.f,0.f,0.f,0.f};
        #pragma unroll
        for (int ks = 0; ks < 4; ks++){
            const int gp = (ks*4 + q) ^ (col & 7);
            const h8 hb = *(const h8*)(&hsw[1][col*128 + gp*8]);
            accz = __builtin_amdgcn_mfma_f32_16x16x32_f16(az[ks], hb, accz, 0, 0, 0);
        }
        #pragma unroll
        for (int r = 0; r < 4; r++){
            const int zi = q*4 + r;
            if (zi < 5) zl[128*80 + zi*16 + col] = accz[r];
        }
    }
    __syncthreads();

    // write zs + mT z-cols
    for (int idx = tid; idx < T_CURN*80; idx += 1024){
        const int t   = idx / 80;
        const int rem = idx - t*80;
        const int zi  = rem >> 4;
        const int bt  = rem & 15;
        const float z = zl[idx] + b_z[zi];
        const int n   = t*BATCH + b0 + bt;
        zs_out[(size_t)n*N_CONF + zi] = z;
        mT[(size_t)n*40 + zi] = (_Float16)z;
    }
}

// ================= octet scan (R10-verified fallback) =============================
__global__ __launch_bounds__(1024, 4) void lstm_scan_oct(
    const float* __restrict__ h0, const float* __restrict__ c0,
    const float* __restrict__ z0,
    const float* __restrict__ W_ih, const float* __restrict__ W_hh,
    const float* __restrict__ b_ih, const float* __restrict__ b_hh,
    const float* __restrict__ W_z, const float* __restrict__ b_z,
    const _Float16* __restrict__ Gx,
    float* __restrict__ zs_out, _Float16* __restrict__ mT)
{
    const int b   = blockIdx.x;
    const int tid = threadIdx.x;
    const int u   = tid >> 3;
    const int r   = tid & 7;
    const int gsel = r >> 1;
    const int gate_l = (gsel << 7) + u;

    __shared__ alignas(16) unsigned short v16h[2][128];
    __shared__ alignas(16) unsigned short hall[T_CURN*136];
    __shared__ alignas(16) unsigned short gxc[2][16*512];
    __shared__ alignas(16) float wzf[5*HID];
    __shared__ alignas(16) _Float16 wz16[5*HID];
    __shared__ float z0c[5];

    for (int i = tid; i < 5*HID; i += 1024){
        const float v = W_z[i];
        wzf[i]  = v;
        wz16[i] = (_Float16)v;
    }
    if (tid < HID) v16h[0][tid] = f2us(h0[tid]);
    if (tid < 5){
        float acc0 = 0.0f, acc1 = 0.0f;
        #pragma unroll 8
        for (int k = 0; k < HID; k += 2){
            acc0 += W_z[tid*HID + k]     * h0[k];
            acc1 += W_z[tid*HID + k + 1] * h0[k + 1];
        }
        z0c[tid] = z0[tid] - b_z[tid] - (acc0 + acc1);
    }
    {
        const int row = tid >> 6;
        const uint4 p = *(const uint4*)(Gx + ((size_t)b*T_CURN + row)*512 + (size_t)(tid & 63)*8);
        *(uint4*)(&gxc[0][(row << 9) + (tid & 63)*8]) = p;
    }
    __syncthreads();

    const int kbase = r << 4;
    h2 wi_[8], wf_[8], wg_[8], wo_[8];
    {
        float zA[5], zB[5], zC[5], zD[5];
        #pragma unroll
        for (int z = 0; z < 5; z++){
            zA[z] = W_ih[(u      )*D_CELL + D_IN + z];
            zB[z] = W_ih[(128 + u)*D_CELL + D_IN + z];
            zC[z] = W_ih[(256 + u)*D_CELL + D_IN + z];
            zD[z] = W_ih[(384 + u)*D_CELL + D_IN + z];
        }
        const float* whA = W_hh + (u      )*HID + kbase;
        const float* whB = W_hh + (128 + u)*HID + kbase;
        const float* whC = W_hh + (256 + u)*HID + kbase;
        const float* whD = W_hh + (384 + u)*HID + kbase;
        #pragma unroll
        for (int i = 0; i < 8; i++){
            const int k = kbase + 2*i;
            float a0 = whA[2*i], a1 = whA[2*i+1];
            float b0 = whB[2*i], b1 = whB[2*i+1];
            float c0v = whC[2*i], c1 = whC[2*i+1];
            float d0 = whD[2*i], d1 = whD[2*i+1];
            #pragma unroll
            for (int z = 0; z < 5; z++){
                const float w0v = wzf[z*HID + k], w1v = wzf[z*HID + k + 1];
                a0 += zA[z]*w0v;  a1 += zA[z]*w1v;
                b0 += zB[z]*w0v;  b1 += zB[z]*w1v;
                c0v += zC[z]*w0v; c1 += zC[z]*w1v;
                d0 += zD[z]*w0v;  d1 += zD[z]*w1v;
            }
            h2 p;
            p.x = (_Float16)a0;  p.y = (_Float16)a1;  wi_[i] = p;
            p.x = (_Float16)b0;  p.y = (_Float16)b1;  wf_[i] = p;
            p.x = (_Float16)c0v; p.y = (_Float16)c1;  wg_[i] = p;
            p.x = (_Float16)d0;  p.y = (_Float16)d1;  wo_[i] = p;
        }
    }
    float be_l, b0_l;
    {
        float w0v = W_ih[gate_l*D_CELL + D_IN + 0];
        float w1v = W_ih[gate_l*D_CELL + D_IN + 1];
        float w2v = W_ih[gate_l*D_CELL + D_IN + 2];
        float w3v = W_ih[gate_l*D_CELL + D_IN + 3];
        float w4v = W_ih[gate_l*D_CELL + D_IN + 4];
        float be = b_ih[gate_l] + b_hh[gate_l]
                 + w0v*b_z[0] + w1v*b_z[1] + w2v*b_z[2] + w3v*b_z[3] + w4v*b_z[4];
        const float d0 = w0v*z0c[0] + w1v*z0c[1] + w2v*z0c[2] + w3v*z0c[3] + w4v*z0c[4];
        be_l = be;
        b0_l = be + d0;
    }
    float c = c0[u];

    for (int t = 0; t < T_CURN; t++){
        const int cb = (t >> 4) & 1;
        uint4 pre;
        bool pok = false;
        if ((t & 15) == 0){
            const int row = t + 16 + (tid >> 6);
            pok = (row < T_CURN);
            if (pok)
                pre = *(const uint4*)(Gx + ((size_t)b*T_CURN + row)*512 + (size_t)(tid & 63)*8);
        }

        const uint4* vb = (const uint4*)(&v16h[t & 1][kbase]);
        const uint4 q0 = vb[0];
        const uint4 q1 = vb[1];
        float ai = 0.f, af = 0.f, ag = 0.f, ao = 0.f;
        ai = dot2f(wi_[0], us2h2(q0.x), ai); ai = dot2f(wi_[1], us2h2(q0.y), ai);
        ai = dot2f(wi_[2], us2h2(q0.z), ai); ai = dot2f(wi_[3], us2h2(q0.w), ai);
        ai = dot2f(wi_[4], us2h2(q1.x), ai); ai = dot2f(wi_[5], us2h2(q1.y), ai);
        ai = dot2f(wi_[6], us2h2(q1.z), ai); ai = dot2f(wi_[7], us2h2(q1.w), ai);
        af = dot2f(wf_[0], us2h2(q0.x), af); af = dot2f(wf_[1], us2h2(q0.y), af);
        af = dot2f(wf_[2], us2h2(q0.z), af); af = dot2f(wf_[3], us2h2(q0.w), af);
        af = dot2f(wf_[4], us2h2(q1.x), af); af = dot2f(wf_[5], us2h2(q1.y), af);
        af = dot2f(wf_[6], us2h2(q1.z), af); af = dot2f(wf_[7], us2h2(q1.w), af);
        ag = dot2f(wg_[0], us2h2(q0.x), ag); ag = dot2f(wg_[1], us2h2(q0.y), ag);
        ag = dot2f(wg_[2], us2h2(q0.z), ag); ag = dot2f(wg_[3], us2h2(q0.w), ag);
        ag = dot2f(wg_[4], us2h2(q1.x), ag); ag = dot2f(wg_[5], us2h2(q1.y), ag);
        ag = dot2f(wg_[6], us2h2(q1.z), ag); ag = dot2f(wg_[7], us2h2(q1.w), ag);
        ao = dot2f(wo_[0], us2h2(q0.x), ao); ao = dot2f(wo_[1], us2h2(q0.y), ao);
        ao = dot2f(wo_[2], us2h2(q0.z), ao); ao = dot2f(wo_[3], us2h2(q0.w), ao);
        ao = dot2f(wo_[4], us2h2(q1.x), ao); ao = dot2f(wo_[5], us2h2(q1.y), ao);
        ao = dot2f(wo_[6], us2h2(q1.z), ao); ao = dot2f(wo_[7], us2h2(q1.w), ao);

        const bool lo4 = (r & 4) == 0;
        float sA = lo4 ? ag : ai;
        float sB = lo4 ? ao : af;
        const float rA = __shfl_xor(sA, 4);
        const float rB = __shfl_xor(sB, 4);
        const float pA = (lo4 ? ai : ag) + rA;
        const float pB = (lo4 ? af : ao) + rB;
        const bool lo2 = (r & 2) == 0;
        float sC = lo2 ? pB : pA;
        const float rC = __shfl_xor(sC, 2);
        float qv = (lo2 ? pA : pB) + rC;
        float gval = qv + __shfl_xor(qv, 1);

        gval += (t == 0) ? b0_l : be_l;
        gval += (float)*(const _Float16*)(&gxc[cb][((t & 15) << 9) + gate_l]);

        const float earg = (gsel == 2) ? (2.0f*gval) : (-gval);
        const float e = __expf(earg);
        const float dd = rcp_fast(1.0f + e);
        const float av = (gsel == 2) ? (1.0f - 2.0f*dd) : dd;

        const float v1 = __shfl_xor(av, 2);
        const float v2 = __shfl_xor(av, 4);
        const float v3 = __shfl_xor(v1, 4);
        float si, sf, tg, so;
        if (gsel == 0){ si = av; sf = v1; tg = v2; so = v3; }
        else if (gsel == 1){ si = v1; sf = av; tg = v3; so = v2; }
        else if (gsel == 2){ si = v2; sf = v3; tg = av; so = v1; }
        else              { si = v3; sf = v2; tg = v1; so = av; }

        c = sf*c + si*tg;
        const float h = so * tanh_f(c);

        if (r == 0){
            const unsigned short hu = f2us(h);
            v16h[(t + 1) & 1][u] = hu;
            hall[t*136 + u] = hu;
        }
        if (pok)
            *(uint4*)(&gxc[cb ^ 1][((tid >> 6) << 9) + (tid & 63)*8]) = pre;
        __syncthreads();
    }

    for (int idx = tid; idx < T_CURN*N_CONF; idx += 1024){
        const int t  = idx / 5;
        const int zi = idx - t*5;
        const uint4* hr = (const uint4*)(hall + t*136);
        const uint4* wr = (const uint4*)(wz16 + zi*HID);
        float s0 = 0.f, s1 = 0.f;
        #pragma unroll
        for (int i = 0; i < 16; i++){
            const uint4 hq = hr[i];
            const uint4 wq = wr[i];
            s0 = dot2f(us2h2(hq.x), us2h2(wq.x), s0);
            s1 = dot2f(us2h2(hq.y), us2h2(wq.y), s1);
            s0 = dot2f(us2h2(hq.z), us2h2(wq.z), s0);
            s1 = dot2f(us2h2(hq.w), us2h2(wq.w), s1);
        }
        const float z = s0 + s1 + b_z[zi];
        const int n = t*BATCH + b;
        zs_out[(size_t)n*N_CONF + zi] = z;
        if (mT) mT[(size_t)n*40 + zi] = (_Float16)z;
    }
}

// ================= standalone preps (legacy fallback paths) =================
__global__ __launch_bounds__(256) void prepack_w1(const float* __restrict__ dW1,
                                                  _Float16* __restrict__ wsh)
{
    const int tid = blockIdx.x*256 + threadIdx.x;
    const int treat = tid >> 10;
    const int r     = tid & 1023;
    const int ft    = r >> 7;
    const int ks    = (r >> 6) & 1;
    const int l     = r & 63;
    const int col   = ft*16 + (l & 15);
    const int kb    = ks*32 + ((l >> 4) << 3);
    h8 v;
    #pragma unroll
    for (int j = 0; j < 8; j++){
        const int k = kb + j;
        v[j] = (k < 35) ? (_Float16)dW1[(treat*35 + k)*128 + col] : (_Float16)0.0f;
    }
    *(h8*)(wsh + (size_t)tid*8) = v;
}

__global__ __launch_bounds__(256) void mt_cov(const float* __restrict__ cc,
                                              _Float16* __restrict__ mT)
{
    const int idx = blockIdx.x*256 + threadIdx.x;
    const int n   = idx / 5;
    const int oct = idx - n*5;
    const int b = n & 255;
    const int t = n >> 8;
    const float* crow = cc + ((size_t)b*T_CURN + t)*N_COV;
    h8 v;
    #pragma unroll
    for (int j = 0; j < 8; j++){
        const int cj = oct*8 + j;
        v[j] = (cj >= 5 && cj < 35) ? (_Float16)crow[cj - 5] : (_Float16)0.0f;
    }
    *(h8*)(mT + (size_t)n*40 + oct*8) = v;
}

__global__ __launch_bounds__(1024, 4) void lstm_scan_old(
    const float* __restrict__ pc, const float* __restrict__ pt,
    const float* __restrict__ init_input, const float* __restrict__ h0,
    const float* __restrict__ c0, const float* __restrict__ z0,
    const float* __restrict__ W_ih, const float* __restrict__ W_hh,
    const float* __restrict__ b_ih, const float* __restrict__ b_hh,
    const float* __restrict__ W_z, const float* __restrict__ b_z,
    float* __restrict__ zs_out, _Float16* __restrict__ mT)
{
    const int b   = blockIdx.x;
    const int tid = threadIdx.x;
    const int g   = tid >> 1;
    const int hf  = tid & 1;

    __shared__ alignas(16) unsigned short v16[224];
    __shared__ alignas(16) unsigned short xall[T_CURN*88];
    __shared__ alignas(16) unsigned short hall[T_CURN*136];
    __shared__ alignas(16) float gbuf[GATES];
    __shared__ alignas(16) _Float16 wz16[5*HID];
    __shared__ float z0c[5];

    float wzg[5];
    #pragma unroll
    for (int z = 0; z < 5; z++) wzg[z] = W_ih[g*D_CELL + 87 + z];

    float be = b_ih[g] + b_hh[g];
    #pragma unroll
    for (int z = 0; z < 5; z++) be += wzg[z] * b_z[z];

    h2 w[56];
    if (hf == 0){
        #pragma unroll
        for (int i = 0; i < 43; i++){
            h2 p; p.x = (_Float16)W_ih[g*D_CELL + 2*i];
                  p.y = (_Float16)W_ih[g*D_CELL + 2*i + 1];
            w[i] = p;
        }
        { h2 p; p.x = (_Float16)W_ih[g*D_CELL + 86]; p.y = (_Float16)0.0f; w[43] = p; }
        #pragma unroll
        for (int i = 44; i < 56; i++){
            const int u = 2*(i - 44);
            float f0 = W_hh[g*HID + u], f1 = W_hh[g*HID + u + 1];
            #pragma unroll
            for (int z = 0; z < 5; z++){
                f0 += wzg[z]*W_z[z*HID + u];
                f1 += wzg[z]*W_z[z*HID + u + 1];
            }
            h2 p; p.x = (_Float16)f0; p.y = (_Float16)f1;
            w[i] = p;
        }
    } else {
        #pragma unroll
        for (int i = 0; i < 52; i++){
            const int u = 24 + 2*i;
            float f0 = W_hh[g*HID + u], f1 = W_hh[g*HID + u + 1];
            #pragma unroll
            for (int z = 0; z < 5; z++){
                f0 += wzg[z]*W_z[z*HID + u];
                f1 += wzg[z]*W_z[z*HID + u + 1];
            }
            h2 p; p.x = (_Float16)f0; p.y = (_Float16)f1;
            w[i] = p;
        }
        #pragma unroll
        for (int i = 52; i < 56; i++){ h2 p; p.x=(_Float16)0.f; p.y=(_Float16)0.f; w[i]=p; }
    }

    for (int idx = tid; idx < T_CURN*88; idx += 1024){
        const int row = idx / 88;
        const int col = idx - row*88;
        float v = 0.0f;
        if (col < D_IN){
            if (row == 0) v = init_input[col];
            else {
                const int tp = row - 1;
                v = (col < N_COV) ? pc[(b*T_PREVN + tp)*N_COV + col]
                                  : pt[(b*T_PREVN + tp)*N_TREAT + (col - N_COV)];
            }
        }
        xall[idx] = f2us(v);
    }

    float c = 0.0f;
    if (tid < HID){ v16[88 + tid] = f2us(h0[tid]); c = c0[tid]; }
    if (tid >= 216 && tid < 224) v16[tid] = 0;

    if (tid < 5){
        float acc0 = 0.0f, acc1 = 0.0f;
        #pragma unroll 8
        for (int u = 0; u < HID; u += 2){
            acc0 += W_z[tid*HID + u]     * h0[u];
            acc1 += W_z[tid*HID + u + 1] * h0[u + 1];
        }
        z0c[tid] = z0[tid] - b_z[tid] - (acc0 + acc1);
    }
    __syncthreads();

    if (tid >= 128 && tid < 216) v16[tid - 128] = xall[tid - 128];
    float b0 = be;
    #pragma unroll
    for (int z = 0; z < 5; z++) b0 += wzg[z] * z0c[z];
    __syncthreads();

    const unsigned short* vbase = v16 + hf*112;
    for (int t = 0; t < T_CURN; t++){
        float a0 = 0.f, a1 = 0.f, a2 = 0.f, a3 = 0.f;
        #pragma unroll
        for (int i = 0; i < 14; i++){
            const uint4 q = *(const uint4*)(vbase + i*8);
            a0 = dot2f(w[4*i+0], us2h2(q.x), a0);
            a1 = dot2f(w[4*i+1], us2h2(q.y), a1);
            a2 = dot2f(w[4*i+2], us2h2(q.z), a2);
            a3 = dot2f(w[4*i+3], us2h2(q.w), a3);
        }
        float s = (a0 + a1) + (a2 + a3);
        s += __shfl_xor(s, 1);
        if (hf == 0) gbuf[g] = s + ((t == 0) ? b0 : be);
        __syncthreads();

        if (tid < HID){
            const float gi = gbuf[tid];
            const float gf = gbuf[128 + tid];
            const float gg = gbuf[256 + tid];
            const float go = gbuf[384 + tid];
            c = sigmoid_f(gf)*c + sigmoid_f(gi)*tanh_f(gg);
            const float h = sigmoid_f(go)*tanh_f(c);
            const unsigned short hu = f2us(h);
            v16[88 + tid] = hu;
            hall[t*136 + tid] = hu;
        } else if (tid < 216){
            if (t < T_PREVN) v16[tid - 128] = xall[(t + 1)*88 + (tid - 128)];
        }
        __syncthreads();
    }

    for (int i = tid; i < 5*HID; i += 1024) wz16[i] = (_Float16)W_z[i];
    __syncthreads();

    if (tid < T_CURN*N_CONF){
        const int t  = tid / 5;
        const int zi = tid - t*5;
        const uint4* hr = (const uint4*)(hall + t*136);
        const uint4* wr = (const uint4*)(wz16 + zi*HID);
        float a0 = 0.f, a1 = 0.f;
        #pragma unroll
        for (int i = 0; i < 16; i++){
            const uint4 hq = hr[i];
            const uint4 wq = wr[i];
            a0 = dot2f(us2h2(hq.x), us2h2(wq.x), a0);
            a1 = dot2f(us2h2(hq.y), us2h2(wq.y), a1);
            a0 = dot2f(us2h2(hq.z), us2h2(wq.z), a0);
            a1 = dot2f(us2h2(hq.w), us2h2(wq.w), a1);
        }
        const float z = a0 + a1 + b_z[zi];
        const int n = t*BATCH + b;
        zs_out[(size_t)n*N_CONF + zi] = z;
        if (mT) mT[(size_t)n*40 + zi] = (_Float16)z;
    }
}

// ================= treat-stationary MFMA decoder (unchanged) =================
__global__ __launch_bounds__(256, 2) void decoder_treat(
    const _Float16* __restrict__ mT, const _Float16* __restrict__ wsh,
    const float* __restrict__ db1, const float* __restrict__ dW2,
    const float* __restrict__ db2, float* __restrict__ preds)
{
    const int treat = blockIdx.x;
    const int rg    = blockIdx.y;
    const int w     = threadIdx.x >> 6;
    const int l     = threadIdx.x & 63;
    const int q     = l >> 4;
    const int r16   = l & 15;

    h8 bf0[8], bf1[8];
    const _Float16* bp = wsh + (size_t)treat*8192 + l*8;
    #pragma unroll
    for (int ft = 0; ft < 8; ft++){
        bf0[ft] = *(const h8*)(bp + ft*1024);
        bf1[ft] = *(const h8*)(bp + ft*1024 + 512);
    }
    float b1r[8], w2r[8], w2c[8];
    #pragma unroll
    for (int ft = 0; ft < 8; ft++){
        b1r[ft] = db1[treat*128 + ft*16 + r16];
        w2r[ft] = dW2[treat*128 + ft*16 + r16];
        w2c[ft] = 0.01f * w2r[ft];
    }
    const float b2 = db2[treat];

    const int tend = (rg + 1)*258;
    for (int tile = rg*258 + w; tile < tend; tile += 4){
        const int n = tile*16 + r16;
        const _Float16* mrow = mT + (size_t)n*40;
        const h8 a0 = *(const h8*)(mrow + q*8);
        h8 a1 = {};
        if (q == 0){
            const h4 t4 = *(const h4*)(mrow + 32);
            a1[0] = t4[0]; a1[1] = t4[1]; a1[2] = t4[2]; a1[3] = t4[3];
        }

        f32x4 pred = {0.f, 0.f, 0.f, 0.f};
        #pragma unroll
        for (int ft = 0; ft < 8; ft++){
            f32x4 acc = {b1r[ft], b1r[ft], b1r[ft], b1r[ft]};
            acc = __builtin_amdgcn_mfma_f32_16x16x32_f16(a0, bf0[ft], acc, 0, 0, 0);
            acc = __builtin_amdgcn_mfma_f32_16x16x32_f16(a1, bf1[ft], acc, 0, 0, 0);
            #pragma unroll
            for (int r = 0; r < 4; r++){
                const float a  = acc[r];
                const float mx = fmaxf(a, 0.0f);
                const float mn = fminf(a, 0.0f);
                pred[r] += mx*w2r[ft] + mn*w2c[ft];
            }
        }
        #pragma unroll
        for (int r = 0; r < 4; r++){
            float s = pred[r];
            s += __shfl_xor(s, 1);
            s += __shfl_xor(s, 2);
            s += __shfl_xor(s, 4);
            s += __shfl_xor(s, 8);
            pred[r] = s;
        }
        if (r16 == 0){
            #pragma unroll
            for (int r = 0; r < 4; r++)
                preds[(size_t)(tile*16 + q*4 + r)*N_TREAT + treat] = pred[r] + b2;
        }
    }
}

// ================= legacy decoder fallback =================
__global__ __launch_bounds__(256) void decoder_fallback(
    const float* __restrict__ cc, const float* __restrict__ zs,
    const float* __restrict__ dW1, const float* __restrict__ db1,
    const float* __restrict__ dW2, const float* __restrict__ db2,
    float* __restrict__ preds)
{
    const int t     = blockIdx.x;
    const int treat = blockIdx.y;
    const int tid   = threadIdx.x;

    __shared__ alignas(16) float w1t[128*36];
    __shared__ float b1s[128];
    __shared__ float w2s[128];

    for (int it = tid; it < 35*128; it += 256){
        const int cidx = it >> 7;
        const int f    = it & 127;
        w1t[f*36 + cidx] = dW1[(treat*35 + cidx)*128 + f];
    }
    if (tid < 128){
        b1s[tid] = db1[treat*128 + tid];
        w2s[tid] = dW2[treat*128 + tid];
        w1t[tid*36 + 35] = 0.0f;
    }
    __syncthreads();

    const int n = t*BATCH + tid;
    float m[36];
    #pragma unroll
    for (int j = 0; j < N_CONF; j++) m[j] = zs[n*N_CONF + j];
    #pragma unroll
    for (int j = 0; j < N_COV; j++)  m[N_CONF + j] = cc[(tid*T_CURN + t)*N_COV + j];
    m[35] = 0.0f;

    const float b2 = db2[treat];
    float pred = 0.0f;
    for (int f = 0; f < 128; f++){
        float a = b1s[f];
        const float4* wr = (const float4*)(w1t + f*36);
        #pragma unroll
        for (int cq = 0; cq < 9; cq++){
            const float4 v = wr[cq];
            a += m[cq*4+0]*v.x + m[cq*4+1]*v.y + m[cq*4+2]*v.z + m[cq*4+3]*v.w;
        }
        a = (a > 0.0f) ? a : 0.01f*a;
        pred += a * w2s[f];
    }
    preds[n*N_TREAT + treat] = pred + b2;
}

extern "C" void kernel_launch(void* const* d_in, const int* in_sizes, int n_in,
                              void* d_out, int out_size, void* d_ws, size_t ws_size,
                              hipStream_t stream)
{
    const float* pc   = (const float*)d_in[0];
    const float* pt   = (const float*)d_in[1];
    const float* cc   = (const float*)d_in[2];
    const float* init = (const float*)d_in[3];
    const float* h0   = (const float*)d_in[4];
    const float* c0   = (const float*)d_in[5];
    const float* z0   = (const float*)d_in[6];
    const float* W_ih = (const float*)d_in[7];
    const float* W_hh = (const float*)d_in[8];
    const float* b_ih = (const float*)d_in[9];
    const float* b_hh = (const float*)d_in[10];
    const float* W_z  = (const float*)d_in[11];
    const float* b_z  = (const float*)d_in[12];
    const float* dW1  = (const float*)d_in[13];
    const float* db1  = (const float*)d_in[14];
    const float* dW2  = (const float*)d_in[15];
    const float* db2  = (const float*)d_in[16];

    float* preds = (float*)d_out;
    float* zs    = (float*)d_out + CONF_OFF;

    if (ws_size >= (size_t)WS_MF){
        _Float16* wsh  = (_Float16*)d_ws;
        _Float16* wihf = (_Float16*)((char*)d_ws + OFF_WIH);
        _Float16* Gx   = (_Float16*)((char*)d_ws + OFF_GX);
        _Float16* mT   = (_Float16*)((char*)d_ws + OFF_MT);
        _Float16* weff = (_Float16*)((char*)d_ws + OFF_WEFF);
        _Float16* wzfr = (_Float16*)((char*)d_ws + OFF_WZF);

        prep_all<<<930, 256, 0, stream>>>(dW1, W_ih, cc, W_hh, W_z,
                                          wsh, wihf, mT, weff, wzfr);
        gx_gemm<<<516, 256, 0, stream>>>(pc, pt, init, wihf, Gx,
                                         W_ih, W_z, b_ih, b_hh, b_z, h0, z0, 1);
        lstm_scan_mfma<<<16, 1024, 0, stream>>>(h0, c0, b_z, weff, wzfr, Gx, zs, mT);
        decoder_treat<<<dim3(N_TREAT, 8), 256, 0, stream>>>(mT, wsh, db1, dW2, db2, preds);
    } else if (ws_size >= (size_t)WS_GX){
        _Float16* wsh  = (_Float16*)d_ws;
        _Float16* wihf = (_Float16*)((char*)d_ws + OFF_WIH);
        _Float16* Gx   = (_Float16*)((char*)d_ws + OFF_GX);
        _Float16* mT   = (_Float16*)((char*)d_ws + OFF_MT);

        prep_all<<<897, 256, 0, stream>>>(dW1, W_ih, cc, W_hh, W_z,
                                          wsh, wihf, mT, (_Float16*)nullptr,
                                          (_Float16*)nullptr);
        gx_gemm<<<516, 256, 0, stream>>>(pc, pt, init, wihf, Gx,
                                         W_ih, W_z, b_ih, b_hh, b_z, h0, z0, 0);
        lstm_scan_oct<<<BATCH, 1024, 0, stream>>>(h0, c0, z0, W_ih, W_hh,
                                                  b_ih, b_hh, W_z, b_z, Gx, zs, mT);
        decoder_treat<<<dim3(N_TREAT, 8), 256, 0, stream>>>(mT, wsh, db1, dW2, db2, preds);
    } else if (ws_size >= (size_t)WS_NEED2){
        _Float16* wsh = (_Float16*)d_ws;
        _Float16* mT  = (_Float16*)((char*)d_ws + WS_NEED);
        prepack_w1<<<228, 256, 0, stream>>>(dW1, wsh);
        mt_cov<<<645, 256, 0, stream>>>(cc, mT);
        lstm_scan_old<<<BATCH, 1024, 0, stream>>>(pc, pt, init, h0, c0, z0,
                                                  W_ih, W_hh, b_ih, b_hh, W_z, b_z, zs, mT);
        decoder_treat<<<dim3(N_TREAT, 8), 256, 0, stream>>>(mT, wsh, db1, dW2, db2, preds);
    } else {
        lstm_scan_old<<<BATCH, 1024, 0, stream>>>(pc, pt, init, h0, c0, z0,
                                                  W_ih, W_hh, b_ih, b_hh, W_z, b_z,
                                                  zs, (_Float16*)nullptr);
        decoder_fallback<<<dim3(T_CURN, N_TREAT), 256, 0, stream>>>(
            cc, zs, dW1, db1, dW2, db2, preds);
    }
}

// Round 12
// 215.297 us; speedup vs baseline: 1.2730x; 1.2730x over previous
//
#include <hip/hip_runtime.h>
#include <stdint.h>

#define BATCH 256
#define T_PREVN 128
#define T_CURN 129
#define N_COV 30
#define N_TREAT 57
#define N_CONF 5
#define HID 128
#define D_IN 87
#define D_CELL 92
#define GATES 512            // 4*H
#define PRED_N (T_CURN*BATCH)        // 33024
#define CONF_OFF (PRED_N*N_TREAT)    // 1882368

// ws layout
#define OFF_W1   0
#define SZ_W1    (57*8*2*64*8*2)             // 933888 B  W1 f16 B-frags
#define OFF_WIH  SZ_W1                        // 933888
#define SZ_WIH   (32*3*64*8*2)                // 98304 B  W_ih f16 B-frags
#define OFF_GX   (OFF_W1 + SZ_W1 + SZ_WIH)    // 1032192
#define SZ_GX    (PRED_N*512*2)               // 33816576 B  Gx f16
#define OFF_MT   (OFF_GX + SZ_GX)             // 34848768
#define SZ_MT    (PRED_N*40*2)                // 2641920 B  mT f16 (fallback tier only)
#define WS_GX    (OFF_MT + SZ_MT)             // 37490688
// legacy gates
#define WS_NEED  SZ_W1
#define WS_NEED2 (SZ_W1 + SZ_MT)

typedef _Float16 h2 __attribute__((ext_vector_type(2)));
typedef _Float16 h4 __attribute__((ext_vector_type(4)));
typedef _Float16 h8 __attribute__((ext_vector_type(8)));
typedef float f32x4 __attribute__((ext_vector_type(4)));

__device__ inline float rcp_fast(float x){
#if __has_builtin(__builtin_amdgcn_rcpf)
    return __builtin_amdgcn_rcpf(x);
#else
    return 1.0f / x;
#endif
}
__device__ inline float sigmoid_f(float x){ return rcp_fast(1.0f + __expf(-x)); }
__device__ inline float tanh_f(float x){ return 1.0f - 2.0f*rcp_fast(1.0f + __expf(2.0f*x)); }

__device__ inline float dot2f(h2 a, h2 b, float c){
#if __has_builtin(__builtin_amdgcn_fdot2)
    return __builtin_amdgcn_fdot2(a, b, c, false);
#else
    return c + (float)a.x*(float)b.x + (float)a.y*(float)b.y;
#endif
}
__device__ inline unsigned short f2us(float v){
    _Float16 h = (_Float16)v;
    return __builtin_bit_cast(unsigned short, h);
}
__device__ inline h2 us2h2(unsigned int u){
    return __builtin_bit_cast(h2, u);
}

// ================= prep: W1 frags + W_ih frags (252 blocks) =================
__global__ __launch_bounds__(256) void prep_w1wih(
    const float* __restrict__ dW1, const float* __restrict__ W_ih,
    _Float16* __restrict__ wsh, _Float16* __restrict__ wihf)
{
    const int bid = blockIdx.x;
    if (bid < 228){
        const int tid = bid*256 + threadIdx.x;
        const int treat = tid >> 10;
        const int r     = tid & 1023;
        const int ft    = r >> 7;
        const int ks    = (r >> 6) & 1;
        const int l     = r & 63;
        const int col   = ft*16 + (l & 15);
        const int kb    = ks*32 + ((l >> 4) << 3);
        h8 v;
        #pragma unroll
        for (int j = 0; j < 8; j++){
            const int k = kb + j;
            v[j] = (k < 35) ? (_Float16)dW1[(treat*35 + k)*128 + col] : (_Float16)0.0f;
        }
        *(h8*)(wsh + (size_t)tid*8) = v;
    } else {
        const int tid = (bid - 228)*256 + threadIdx.x;
        const int ct  = tid / 192;
        const int rem = tid - ct*192;
        const int ks  = rem >> 6;
        const int l   = rem & 63;
        const int gate = ct*16 + (l & 15);
        const int kb   = ks*32 + ((l >> 4) << 3);
        h8 v;
        #pragma unroll
        for (int j = 0; j < 8; j++){
            const int k = kb + j;
            v[j] = (k < D_IN) ? (_Float16)W_ih[gate*D_CELL + k] : (_Float16)0.0f;
        }
        *(h8*)(wihf + (size_t)tid*8) = v;
    }
}

// ================= Gx GEMM (R6 version, verified) =================================
__global__ __launch_bounds__(256, 2) void gx_gemm(
    const float* __restrict__ pc, const float* __restrict__ pt,
    const float* __restrict__ init_input,
    const _Float16* __restrict__ wihf, _Float16* __restrict__ Gx)
{
    __shared__ alignas(16) _Float16 a_lds[64*104];
    __shared__ alignas(16) _Float16 gx_lds[64*264];

    const int tid = threadIdx.x;
    const int nb  = blockIdx.x * 64;

    for (int idx = tid; idx < 64*96; idx += 256){
        const int r = idx / 96;
        const int k = idx - r*96;
        const int n = nb + r;
        const int bb = n / 129;
        const int t  = n - bb*129;
        float v = 0.0f;
        if (k < D_IN){
            if (t == 0) v = init_input[k];
            else        v = (k < N_COV) ? pc[(bb*T_PREVN + t-1)*N_COV + k]
                                        : pt[(bb*T_PREVN + t-1)*N_TREAT + (k - N_COV)];
        }
        a_lds[r*104 + k] = (_Float16)v;
    }
    __syncthreads();

    const int w    = tid >> 6;
    const int l    = tid & 63;
    const int col  = l & 15;
    const int quad = l >> 4;

    const _Float16* ar = a_lds + (w*16 + col)*104 + quad*8;
    const h8 a0 = *(const h8*)(ar);
    const h8 a1 = *(const h8*)(ar + 32);
    const h8 a2 = *(const h8*)(ar + 64);

    for (int half = 0; half < 2; half++){
        #pragma unroll
        for (int ct8 = 0; ct8 < 16; ct8++){
            const int ct = half*16 + ct8;
            const _Float16* bp = wihf + (size_t)ct*1536 + l*8;
            const h8 b0 = *(const h8*)(bp);
            const h8 b1 = *(const h8*)(bp + 512);
            const h8 b2 = *(const h8*)(bp + 1024);
            f32x4 acc = {0.f, 0.f, 0.f, 0.f};
            acc = __builtin_amdgcn_mfma_f32_16x16x32_f16(a0, b0, acc, 0, 0, 0);
            acc = __builtin_amdgcn_mfma_f32_16x16x32_f16(a1, b1, acc, 0, 0, 0);
            acc = __builtin_amdgcn_mfma_f32_16x16x32_f16(a2, b2, acc, 0, 0, 0);
            #pragma unroll
            for (int r4 = 0; r4 < 4; r4++)
                gx_lds[(w*16 + quad*4 + r4)*264 + ct8*16 + col] = (_Float16)acc[r4];
        }
        __syncthreads();
        #pragma unroll
        for (int it = 0; it < 8; it++){
            const int idx = it*256 + tid;
            const int r   = idx >> 5;
            const int seg = idx & 31;
            *(h8*)(Gx + ((size_t)(nb + r))*512 + half*256 + seg*8) =
                *(const h8*)(&gx_lds[r*264 + seg*8]);
        }
        __syncthreads();
    }
}

// ================= FUSED: R6 scan (verbatim) + in-block decoder tail ==============
// Main loop = lstm_scan_gx (R6, 120us verified). Tail: build m_lds[144][40]
// (z from post-pass, cov from cc), then decoder_treat's math verbatim with
// A-loads from LDS; wave w handles treats {w, w+16, ...}. No mT, no extra dispatch.
__global__ __launch_bounds__(1024, 4) void lstm_scan_fused(
    const float* __restrict__ h0, const float* __restrict__ c0,
    const float* __restrict__ z0,
    const float* __restrict__ W_ih, const float* __restrict__ W_hh,
    const float* __restrict__ b_ih, const float* __restrict__ b_hh,
    const float* __restrict__ W_z, const float* __restrict__ b_z,
    const _Float16* __restrict__ Gx, const float* __restrict__ cc,
    const _Float16* __restrict__ wsh, const float* __restrict__ db1,
    const float* __restrict__ dW2, const float* __restrict__ db2,
    float* __restrict__ zs_out, float* __restrict__ preds)
{
    const int b   = blockIdx.x;
    const int tid = threadIdx.x;
    const int grp = tid >> 2;          // 256 groups
    const int j   = tid & 3;           // k-slice
    const int g0  = grp*2, g1 = g0 + 1;

    __shared__ alignas(16) unsigned short v16h[128 + 128];   // [2][128] flat
    __shared__ alignas(16) unsigned short hall[T_CURN*136];  // 35088 B
    __shared__ alignas(16) unsigned short gxc[2][16*512];    // 32768 B
    __shared__ alignas(16) float wzf[5*HID];
    __shared__ alignas(16) _Float16 wz16[5*HID];
    __shared__ alignas(16) _Float16 m_lds[144*40];           // 11520 B
    __shared__ float z0c[5];

    for (int i = tid; i < 5*HID; i += 1024){
        const float v = W_z[i];
        wzf[i]  = v;
        wz16[i] = (_Float16)v;
    }
    if (tid < HID) v16h[tid] = f2us(h0[tid]);
    if (tid < 5){
        float acc0 = 0.0f, acc1 = 0.0f;
        #pragma unroll 8
        for (int k = 0; k < HID; k += 2){
            acc0 += W_z[tid*HID + k]     * h0[k];
            acc1 += W_z[tid*HID + k + 1] * h0[k + 1];
        }
        z0c[tid] = z0[tid] - b_z[tid] - (acc0 + acc1);
    }
    // preload Gx chunk 0 (steps 0..15)
    {
        const int row = tid >> 6;
        const uint4 p = *(const uint4*)(Gx + ((size_t)b*T_CURN + row)*512 + (size_t)(tid & 63)*8);
        *(uint4*)(&gxc[0][(row << 9) + (tid & 63)*8]) = p;
    }
    __syncthreads();

    // ---- fold weights: W_eff = W_hh + W_ihz @ W_z (R6 verbatim) ----
    float wz0[5], wz1[5];
    #pragma unroll
    for (int z = 0; z < 5; z++){
        wz0[z] = W_ih[g0*D_CELL + D_IN + z];
        wz1[z] = W_ih[g1*D_CELL + D_IN + z];
    }
    float be0 = b_ih[g0] + b_hh[g0];
    float be1 = b_ih[g1] + b_hh[g1];
    #pragma unroll
    for (int z = 0; z < 5; z++){ be0 += wz0[z]*b_z[z]; be1 += wz1[z]*b_z[z]; }

    h2 w0[16], w1[16];
    {
        const int kb = j*32;
        #pragma unroll
        for (int i = 0; i < 16; i++){
            const int k = kb + 2*i;
            float f00 = W_hh[g0*HID + k],     f01 = W_hh[g0*HID + k + 1];
            float f10 = W_hh[g1*HID + k],     f11 = W_hh[g1*HID + k + 1];
            #pragma unroll
            for (int z = 0; z < 5; z++){
                const float a = wzf[z*HID + k], bb2 = wzf[z*HID + k + 1];
                f00 += wz0[z]*a;  f01 += wz0[z]*bb2;
                f10 += wz1[z]*a;  f11 += wz1[z]*bb2;
            }
            h2 p0; p0.x = (_Float16)f00; p0.y = (_Float16)f01; w0[i] = p0;
            h2 p1; p1.x = (_Float16)f10; p1.y = (_Float16)f11; w1[i] = p1;
        }
    }
    float b00 = be0, b01 = be1;
    #pragma unroll
    for (int z = 0; z < 5; z++){ b00 += wz0[z]*z0c[z]; b01 += wz1[z]*z0c[z]; }

    // ---- main loop (R6 verbatim): 2 barriers/step, Gx chunk refill per 16 steps --
    __shared__ alignas(16) float gbuf[GATES];
    const unsigned short* vb0 = v16h + j*32;
    for (int t = 0; t < T_CURN; t++){
        const int cb = (t >> 4) & 1;
        const unsigned short* vb = vb0 + (t & 1)*128;
        uint4 pre;
        bool pok = false;
        if ((t & 15) == 0){
            const int row = t + 16 + (tid >> 6);
            pok = (row < T_CURN);
            if (pok)
                pre = *(const uint4*)(Gx + ((size_t)b*T_CURN + row)*512 + (size_t)(tid & 63)*8);
        }

        float s0a=0.f, s0b=0.f, s1a=0.f, s1b=0.f;
        #pragma unroll
        for (int i = 0; i < 4; i++){
            const uint4 q = *(const uint4*)(vb + i*8);
            s0a = dot2f(w0[4*i+0], us2h2(q.x), s0a);
            s0b = dot2f(w0[4*i+1], us2h2(q.y), s0b);
            s0a = dot2f(w0[4*i+2], us2h2(q.z), s0a);
            s0b = dot2f(w0[4*i+3], us2h2(q.w), s0b);
            s1a = dot2f(w1[4*i+0], us2h2(q.x), s1a);
            s1b = dot2f(w1[4*i+1], us2h2(q.y), s1b);
            s1a = dot2f(w1[4*i+2], us2h2(q.z), s1a);
            s1b = dot2f(w1[4*i+3], us2h2(q.w), s1b);
        }
        float s0 = s0a + s0b, s1 = s1a + s1b;
        s0 += __shfl_xor(s0, 1);  s0 += __shfl_xor(s0, 2);
        s1 += __shfl_xor(s1, 1);  s1 += __shfl_xor(s1, 2);
        if (j == 0){
            const h2 gx = us2h2(*(const unsigned int*)(&gxc[cb][(t & 15)*512 + g0]));
            float2 gg;
            gg.x = s0 + (float)gx.x + ((t == 0) ? b00 : be0);
            gg.y = s1 + (float)gx.y + ((t == 0) ? b01 : be1);
            *(float2*)(&gbuf[g0]) = gg;
        }
        __syncthreads();

        if (tid < HID){
            const float gi = gbuf[tid];
            const float gf = gbuf[128 + tid];
            const float gg = gbuf[256 + tid];
            const float go = gbuf[384 + tid];
            float c = (t == 0) ? c0[tid]
                               : __builtin_bit_cast(float, *(const unsigned int*)(&gbuf[0]) ) ;
            // NOTE: c must persist across steps; keep in register below instead.
            (void)c;
        }
        // c persistence handled by dedicated registers on threads < 128:
        __syncthreads();
        // placeholder removed below
        if (pok) *(uint4*)(&gxc[cb ^ 1][tid*8]) = pre;
        if (false) {}
        break;  // unreachable guard (restructured loop below)
    }

    // --- restructured main loop with persistent c (actual execution path) ---
    {
        float c = (tid < HID) ? c0[tid] : 0.0f;
        for (int t = 0; t < T_CURN; t++){
            const int cb = (t >> 4) & 1;
            const unsigned short* vb = vb0 + (t & 1)*128;
            uint4 pre;
            bool pok = false;
            if ((t & 15) == 0){
                const int row = t + 16 + (tid >> 6);
                pok = (row < T_CURN);
                if (pok)
                    pre = *(const uint4*)(Gx + ((size_t)b*T_CURN + row)*512 + (size_t)(tid & 63)*8);
            }

            float s0a=0.f, s0b=0.f, s1a=0.f, s1b=0.f;
            #pragma unroll
            for (int i = 0; i < 4; i++){
                const uint4 q = *(const uint4*)(vb + i*8);
                s0a = dot2f(w0[4*i+0], us2h2(q.x), s0a);
                s0b = dot2f(w0[4*i+1], us2h2(q.y), s0b);
                s0a = dot2f(w0[4*i+2], us2h2(q.z), s0a);
                s0b = dot2f(w0[4*i+3], us2h2(q.w), s0b);
                s1a = dot2f(w1[4*i+0], us2h2(q.x), s1a);
                s1b = dot2f(w1[4*i+1], us2h2(q.y), s1b);
                s1a = dot2f(w1[4*i+2], us2h2(q.z), s1a);
                s1b = dot2f(w1[4*i+3], us2h2(q.w), s1b);
            }
            float s0 = s0a + s0b, s1 = s1a + s1b;
            s0 += __shfl_xor(s0, 1);  s0 += __shfl_xor(s0, 2);
            s1 += __shfl_xor(s1, 1);  s1 += __shfl_xor(s1, 2);
            if (j == 0){
                const h2 gx = us2h2(*(const unsigned int*)(&gxc[cb][(t & 15)*512 + g0]));
                float2 gg;
                gg.x = s0 + (float)gx.x + ((t == 0) ? b00 : be0);
                gg.y = s1 + (float)gx.y + ((t == 0) ? b01 : be1);
                *(float2*)(&gbuf[g0]) = gg;
            }
            __syncthreads();

            if (tid < HID){
                const float gi = gbuf[tid];
                const float gf = gbuf[128 + tid];
                const float gg = gbuf[256 + tid];
                const float go = gbuf[384 + tid];
                c = sigmoid_f(gf)*c + sigmoid_f(gi)*tanh_f(gg);
                const float h = sigmoid_f(go)*tanh_f(c);
                const unsigned short hu = f2us(h);
                v16h[((t + 1) & 1)*128 + tid] = hu;
                hall[t*136 + tid] = hu;
            }
            if (pok) *(uint4*)(&gxc[cb ^ 1][tid*8]) = pre;
            __syncthreads();
        }
    }

    // ---- z post-pass -> zs_out + m_lds z cols ----
    if (tid < T_CURN*N_CONF){
        const int t  = tid / 5;
        const int zi = tid - t*5;
        const uint4* hr = (const uint4*)(hall + t*136);
        const uint4* wr = (const uint4*)(wz16 + zi*HID);
        float s0 = 0.f, s1 = 0.f;
        #pragma unroll
        for (int i = 0; i < 16; i++){
            const uint4 hq = hr[i];
            const uint4 wq = wr[i];
            s0 = dot2f(us2h2(hq.x), us2h2(wq.x), s0);
            s1 = dot2f(us2h2(hq.y), us2h2(wq.y), s1);
            s0 = dot2f(us2h2(hq.z), us2h2(wq.z), s0);
            s1 = dot2f(us2h2(hq.w), us2h2(wq.w), s1);
        }
        const float z = s0 + s1 + b_z[zi];
        zs_out[(size_t)(t*BATCH + b)*N_CONF + zi] = z;
        m_lds[t*40 + zi] = (_Float16)z;
    }
    // cov cols + pads
    for (int idx = tid; idx < 144*40; idx += 1024){
        const int t   = idx / 40;
        const int cjj = idx - t*40;
        if (cjj < 5) continue;
        float v = 0.0f;
        if (t < T_CURN && cjj < 35)
            v = cc[((size_t)b*T_CURN + t)*N_COV + (cjj - 5)];
        m_lds[idx] = (_Float16)v;
    }
    __syncthreads();

    // ---- decode tail (decoder_treat math, A from LDS) ----
    {
        const int wv  = tid >> 6;
        const int l   = tid & 63;
        const int q   = l >> 4;
        const int r16 = l & 15;

        for (int treat = wv; treat < N_TREAT; treat += 16){
            h8 bf0[8], bf1[8];
            const _Float16* bp = wsh + (size_t)treat*8192 + l*8;
            #pragma unroll
            for (int ft = 0; ft < 8; ft++){
                bf0[ft] = *(const h8*)(bp + ft*1024);
                bf1[ft] = *(const h8*)(bp + ft*1024 + 512);
            }
            float b1r[8], w2r[8], w2c[8];
            #pragma unroll
            for (int ft = 0; ft < 8; ft++){
                b1r[ft] = db1[treat*128 + ft*16 + r16];
                w2r[ft] = dW2[treat*128 + ft*16 + r16];
                w2c[ft] = 0.01f * w2r[ft];
            }
            const float b2 = db2[treat];

            for (int tile = 0; tile < 9; tile++){
                const _Float16* mrow = m_lds + (tile*16 + r16)*40;
                const h8 a0 = *(const h8*)(mrow + q*8);
                h8 a1 = {};
                if (q == 0){
                    const h4 t4 = *(const h4*)(mrow + 32);
                    a1[0] = t4[0]; a1[1] = t4[1]; a1[2] = t4[2]; a1[3] = t4[3];
                }

                f32x4 pred = {0.f, 0.f, 0.f, 0.f};
                #pragma unroll
                for (int ft = 0; ft < 8; ft++){
                    f32x4 acc = {b1r[ft], b1r[ft], b1r[ft], b1r[ft]};
                    acc = __builtin_amdgcn_mfma_f32_16x16x32_f16(a0, bf0[ft], acc, 0, 0, 0);
                    acc = __builtin_amdgcn_mfma_f32_16x16x32_f16(a1, bf1[ft], acc, 0, 0, 0);
                    #pragma unroll
                    for (int r = 0; r < 4; r++){
                        const float a  = acc[r];
                        const float mx = fmaxf(a, 0.0f);
                        const float mn = fminf(a, 0.0f);
                        pred[r] += mx*w2r[ft] + mn*w2c[ft];
                    }
                }
                #pragma unroll
                for (int r = 0; r < 4; r++){
                    float s = pred[r];
                    s += __shfl_xor(s, 1);
                    s += __shfl_xor(s, 2);
                    s += __shfl_xor(s, 4);
                    s += __shfl_xor(s, 8);
                    pred[r] = s;
                }
                if (r16 == 0){
                    #pragma unroll
                    for (int r = 0; r < 4; r++){
                        const int t = tile*16 + q*4 + r;
                        if (t < T_CURN)
                            preds[((size_t)t*BATCH + b)*N_TREAT + treat] = pred[r] + b2;
                    }
                }
            }
        }
    }
}

// ================= fallbacks (lower ws tiers) =================
__global__ __launch_bounds__(256) void prepack_w1(const float* __restrict__ dW1,
                                                  _Float16* __restrict__ wsh)
{
    const int tid = blockIdx.x*256 + threadIdx.x;
    const int treat = tid >> 10;
    const int r     = tid & 1023;
    const int ft    = r >> 7;
    const int ks    = (r >> 6) & 1;
    const int l     = r & 63;
    const int col   = ft*16 + (l & 15);
    const int kb    = ks*32 + ((l >> 4) << 3);
    h8 v;
    #pragma unroll
    for (int j = 0; j < 8; j++){
        const int k = kb + j;
        v[j] = (k < 35) ? (_Float16)dW1[(treat*35 + k)*128 + col] : (_Float16)0.0f;
    }
    *(h8*)(wsh + (size_t)tid*8) = v;
}

__global__ __launch_bounds__(256) void mt_cov(const float* __restrict__ cc,
                                              _Float16* __restrict__ mT)
{
    const int idx = blockIdx.x*256 + threadIdx.x;
    const int n   = idx / 5;
    const int oct = idx - n*5;
    const int b = n & 255;
    const int t = n >> 8;
    const float* crow = cc + ((size_t)b*T_CURN + t)*N_COV;
    h8 v;
    #pragma unroll
    for (int j = 0; j < 8; j++){
        const int cj = oct*8 + j;
        v[j] = (cj >= 5 && cj < 35) ? (_Float16)crow[cj - 5] : (_Float16)0.0f;
    }
    *(h8*)(mT + (size_t)n*40 + oct*8) = v;
}

__global__ __launch_bounds__(1024, 4) void lstm_scan_old(
    const float* __restrict__ pc, const float* __restrict__ pt,
    const float* __restrict__ init_input, const float* __restrict__ h0,
    const float* __restrict__ c0, const float* __restrict__ z0,
    const float* __restrict__ W_ih, const float* __restrict__ W_hh,
    const float* __restrict__ b_ih, const float* __restrict__ b_hh,
    const float* __restrict__ W_z, const float* __restrict__ b_z,
    float* __restrict__ zs_out, _Float16* __restrict__ mT)
{
    const int b   = blockIdx.x;
    const int tid = threadIdx.x;
    const int g   = tid >> 1;
    const int hf  = tid & 1;

    __shared__ alignas(16) unsigned short v16[224];
    __shared__ alignas(16) unsigned short xall[T_CURN*88];
    __shared__ alignas(16) unsigned short hall[T_CURN*136];
    __shared__ alignas(16) float gbuf[GATES];
    __shared__ alignas(16) _Float16 wz16[5*HID];
    __shared__ float z0c[5];

    float wzg[5];
    #pragma unroll
    for (int z = 0; z < 5; z++) wzg[z] = W_ih[g*D_CELL + 87 + z];

    float be = b_ih[g] + b_hh[g];
    #pragma unroll
    for (int z = 0; z < 5; z++) be += wzg[z] * b_z[z];

    h2 w[56];
    if (hf == 0){
        #pragma unroll
        for (int i = 0; i < 43; i++){
            h2 p; p.x = (_Float16)W_ih[g*D_CELL + 2*i];
                  p.y = (_Float16)W_ih[g*D_CELL + 2*i + 1];
            w[i] = p;
        }
        { h2 p; p.x = (_Float16)W_ih[g*D_CELL + 86]; p.y = (_Float16)0.0f; w[43] = p; }
        #pragma unroll
        for (int i = 44; i < 56; i++){
            const int u = 2*(i - 44);
            float f0 = W_hh[g*HID + u], f1 = W_hh[g*HID + u + 1];
            #pragma unroll
            for (int z = 0; z < 5; z++){
                f0 += wzg[z]*W_z[z*HID + u];
                f1 += wzg[z]*W_z[z*HID + u + 1];
            }
            h2 p; p.x = (_Float16)f0; p.y = (_Float16)f1;
            w[i] = p;
        }
    } else {
        #pragma unroll
        for (int i = 0; i < 52; i++){
            const int u = 24 + 2*i;
            float f0 = W_hh[g*HID + u], f1 = W_hh[g*HID + u + 1];
            #pragma unroll
            for (int z = 0; z < 5; z++){
                f0 += wzg[z]*W_z[z*HID + u];
                f1 += wzg[z]*W_z[z*HID + u + 1];
            }
            h2 p; p.x = (_Float16)f0; p.y = (_Float16)f1;
            w[i] = p;
        }
        #pragma unroll
        for (int i = 52; i < 56; i++){ h2 p; p.x=(_Float16)0.f; p.y=(_Float16)0.f; w[i]=p; }
    }

    for (int idx = tid; idx < T_CURN*88; idx += 1024){
        const int row = idx / 88;
        const int col = idx - row*88;
        float v = 0.0f;
        if (col < D_IN){
            if (row == 0) v = init_input[col];
            else {
                const int tp = row - 1;
                v = (col < N_COV) ? pc[(b*T_PREVN + tp)*N_COV + col]
                                  : pt[(b*T_PREVN + tp)*N_TREAT + (col - N_COV)];
            }
        }
        xall[idx] = f2us(v);
    }

    float c = 0.0f;
    if (tid < HID){ v16[88 + tid] = f2us(h0[tid]); c = c0[tid]; }
    if (tid >= 216 && tid < 224) v16[tid] = 0;

    if (tid < 5){
        float acc0 = 0.0f, acc1 = 0.0f;
        #pragma unroll 8
        for (int u = 0; u < HID; u += 2){
            acc0 += W_z[tid*HID + u]     * h0[u];
            acc1 += W_z[tid*HID + u + 1] * h0[u + 1];
        }
        z0c[tid] = z0[tid] - b_z[tid] - (acc0 + acc1);
    }
    __syncthreads();

    if (tid >= 128 && tid < 216) v16[tid - 128] = xall[tid - 128];
    float b0 = be;
    #pragma unroll
    for (int z = 0; z < 5; z++) b0 += wzg[z] * z0c[z];
    __syncthreads();

    const unsigned short* vbase = v16 + hf*112;
    for (int t = 0; t < T_CURN; t++){
        float a0 = 0.f, a1 = 0.f, a2 = 0.f, a3 = 0.f;
        #pragma unroll
        for (int i = 0; i < 14; i++){
            const uint4 q = *(const uint4*)(vbase + i*8);
            a0 = dot2f(w[4*i+0], us2h2(q.x), a0);
            a1 = dot2f(w[4*i+1], us2h2(q.y), a1);
            a2 = dot2f(w[4*i+2], us2h2(q.z), a2);
            a3 = dot2f(w[4*i+3], us2h2(q.w), a3);
        }
        float s = (a0 + a1) + (a2 + a3);
        s += __shfl_xor(s, 1);
        if (hf == 0) gbuf[g] = s + ((t == 0) ? b0 : be);
        __syncthreads();

        if (tid < HID){
            const float gi = gbuf[tid];
            const float gf = gbuf[128 + tid];
            const float gg = gbuf[256 + tid];
            const float go = gbuf[384 + tid];
            c = sigmoid_f(gf)*c + sigmoid_f(gi)*tanh_f(gg);
            const float h = sigmoid_f(go)*tanh_f(c);
            const unsigned short hu = f2us(h);
            v16[88 + tid] = hu;
            hall[t*136 + tid] = hu;
        } else if (tid < 216){
            if (t < T_PREVN) v16[tid - 128] = xall[(t + 1)*88 + (tid - 128)];
        }
        __syncthreads();
    }

    for (int i = tid; i < 5*HID; i += 1024) wz16[i] = (_Float16)W_z[i];
    __syncthreads();

    if (tid < T_CURN*N_CONF){
        const int t  = tid / 5;
        const int zi = tid - t*5;
        const uint4* hr = (const uint4*)(hall + t*136);
        const uint4* wr = (const uint4*)(wz16 + zi*HID);
        float a0 = 0.f, a1 = 0.f;
        #pragma unroll
        for (int i = 0; i < 16; i++){
            const uint4 hq = hr[i];
            const uint4 wq = wr[i];
            a0 = dot2f(us2h2(hq.x), us2h2(wq.x), a0);
            a1 = dot2f(us2h2(hq.y), us2h2(wq.y), a1);
            a0 = dot2f(us2h2(hq.z), us2h2(wq.z), a0);
            a1 = dot2f(us2h2(hq.w), us2h2(wq.w), a1);
        }
        const float z = a0 + a1 + b_z[zi];
        const int n = t*BATCH + b;
        zs_out[(size_t)n*N_CONF + zi] = z;
        if (mT) mT[(size_t)n*40 + zi] = (_Float16)z;
    }
}

__global__ __launch_bounds__(256, 2) void decoder_treat(
    const _Float16* __restrict__ mT, const _Float16* __restrict__ wsh,
    const float* __restrict__ db1, const float* __restrict__ dW2,
    const float* __restrict__ db2, float* __restrict__ preds)
{
    const int treat = blockIdx.x;
    const int rg    = blockIdx.y;
    const int w     = threadIdx.x >> 6;
    const int l     = threadIdx.x & 63;
    const int q     = l >> 4;
    const int r16   = l & 15;

    h8 bf0[8], bf1[8];
    const _Float16* bp = wsh + (size_t)treat*8192 + l*8;
    #pragma unroll
    for (int ft = 0; ft < 8; ft++){
        bf0[ft] = *(const h8*)(bp + ft*1024);
        bf1[ft] = *(const h8*)(bp + ft*1024 + 512);
    }
    float b1r[8], w2r[8], w2c[8];
    #pragma unroll
    for (int ft = 0; ft < 8; ft++){
        b1r[ft] = db1[treat*128 + ft*16 + r16];
        w2r[ft] = dW2[treat*128 + ft*16 + r16];
        w2c[ft] = 0.01f * w2r[ft];
    }
    const float b2 = db2[treat];

    const int tend = (rg + 1)*258;
    for (int tile = rg*258 + w; tile < tend; tile += 4){
        const int n = tile*16 + r16;
        const _Float16* mrow = mT + (size_t)n*40;
        const h8 a0 = *(const h8*)(mrow + q*8);
        h8 a1 = {};
        if (q == 0){
            const h4 t4 = *(const h4*)(mrow + 32);
            a1[0] = t4[0]; a1[1] = t4[1]; a1[2] = t4[2]; a1[3] = t4[3];
        }

        f32x4 pred = {0.f, 0.f, 0.f, 0.f};
        #pragma unroll
        for (int ft = 0; ft < 8; ft++){
            f32x4 acc = {b1r[ft], b1r[ft], b1r[ft], b1r[ft]};
            acc = __builtin_amdgcn_mfma_f32_16x16x32_f16(a0, bf0[ft], acc, 0, 0, 0);
            acc = __builtin_amdgcn_mfma_f32_16x16x32_f16(a1, bf1[ft], acc, 0, 0, 0);
            #pragma unroll
            for (int r = 0; r < 4; r++){
                const float a  = acc[r];
                const float mx = fmaxf(a, 0.0f);
                const float mn = fminf(a, 0.0f);
                pred[r] += mx*w2r[ft] + mn*w2c[ft];
            }
        }
        #pragma unroll
        for (int r = 0; r < 4; r++){
            float s = pred[r];
            s += __shfl_xor(s, 1);
            s += __shfl_xor(s, 2);
            s += __shfl_xor(s, 4);
            s += __shfl_xor(s, 8);
            pred[r] = s;
        }
        if (r16 == 0){
            #pragma unroll
            for (int r = 0; r < 4; r++)
                preds[(size_t)(tile*16 + q*4 + r)*N_TREAT + treat] = pred[r] + b2;
        }
    }
}

__global__ __launch_bounds__(256) void decoder_fallback(
    const float* __restrict__ cc, const float* __restrict__ zs,
    const float* __restrict__ dW1, const float* __restrict__ db1,
    const float* __restrict__ dW2, const float* __restrict__ db2,
    float* __restrict__ preds)
{
    const int t     = blockIdx.x;
    const int treat = blockIdx.y;
    const int tid   = threadIdx.x;

    __shared__ alignas(16) float w1t[128*36];
    __shared__ float b1s[128];
    __shared__ float w2s[128];

    for (int it = tid; it < 35*128; it += 256){
        const int cidx = it >> 7;
        const int f    = it & 127;
        w1t[f*36 + cidx] = dW1[(treat*35 + cidx)*128 + f];
    }
    if (tid < 128){
        b1s[tid] = db1[treat*128 + tid];
        w2s[tid] = dW2[treat*128 + tid];
        w1t[tid*36 + 35] = 0.0f;
    }
    __syncthreads();

    const int n = t*BATCH + tid;
    float m[36];
    #pragma unroll
    for (int j = 0; j < N_CONF; j++) m[j] = zs[n*N_CONF + j];
    #pragma unroll
    for (int j = 0; j < N_COV; j++)  m[N_CONF + j] = cc[(tid*T_CURN + t)*N_COV + j];
    m[35] = 0.0f;

    const float b2 = db2[treat];
    float pred = 0.0f;
    for (int f = 0; f < 128; f++){
        float a = b1s[f];
        const float4* wr = (const float4*)(w1t + f*36);
        #pragma unroll
        for (int cq = 0; cq < 9; cq++){
            const float4 v = wr[cq];
            a += m[cq*4+0]*v.x + m[cq*4+1]*v.y + m[cq*4+2]*v.z + m[cq*4+3]*v.w;
        }
        a = (a > 0.0f) ? a : 0.01f*a;
        pred += a * w2s[f];
    }
    preds[n*N_TREAT + treat] = pred + b2;
}

extern "C" void kernel_launch(void* const* d_in, const int* in_sizes, int n_in,
                              void* d_out, int out_size, void* d_ws, size_t ws_size,
                              hipStream_t stream)
{
    const float* pc   = (const float*)d_in[0];
    const float* pt   = (const float*)d_in[1];
    const float* cc   = (const float*)d_in[2];
    const float* init = (const float*)d_in[3];
    const float* h0   = (const float*)d_in[4];
    const float* c0   = (const float*)d_in[5];
    const float* z0   = (const float*)d_in[6];
    const float* W_ih = (const float*)d_in[7];
    const float* W_hh = (const float*)d_in[8];
    const float* b_ih = (const float*)d_in[9];
    const float* b_hh = (const float*)d_in[10];
    const float* W_z  = (const float*)d_in[11];
    const float* b_z  = (const float*)d_in[12];
    const float* dW1  = (const float*)d_in[13];
    const float* db1  = (const float*)d_in[14];
    const float* dW2  = (const float*)d_in[15];
    const float* db2  = (const float*)d_in[16];

    float* preds = (float*)d_out;
    float* zs    = (float*)d_out + CONF_OFF;

    if (ws_size >= (size_t)WS_GX){
        _Float16* wsh  = (_Float16*)d_ws;
        _Float16* wihf = (_Float16*)((char*)d_ws + OFF_WIH);
        _Float16* Gx   = (_Float16*)((char*)d_ws + OFF_GX);

        prep_w1wih<<<252, 256, 0, stream>>>(dW1, W_ih, wsh, wihf);
        gx_gemm<<<516, 256, 0, stream>>>(pc, pt, init, wihf, Gx);
        lstm_scan_fused<<<BATCH, 1024, 0, stream>>>(h0, c0, z0, W_ih, W_hh,
                                                    b_ih, b_hh, W_z, b_z, Gx, cc,
                                                    wsh, db1, dW2, db2, zs, preds);
    } else if (ws_size >= (size_t)WS_NEED2){
        _Float16* wsh = (_Float16*)d_ws;
        _Float16* mT  = (_Float16*)((char*)d_ws + WS_NEED);
        prepack_w1<<<228, 256, 0, stream>>>(dW1, wsh);
        mt_cov<<<645, 256, 0, stream>>>(cc, mT);
        lstm_scan_old<<<BATCH, 1024, 0, stream>>>(pc, pt, init, h0, c0, z0,
                                                  W_ih, W_hh, b_ih, b_hh, W_z, b_z, zs, mT);
        decoder_treat<<<dim3(N_TREAT, 8), 256, 0, stream>>>(mT, wsh, db1, dW2, db2, preds);
    } else {
        lstm_scan_old<<<BATCH, 1024, 0, stream>>>(pc, pt, init, h0, c0, z0,
                                                  W_ih, W_hh, b_ih, b_hh, W_z, b_z,
                                                  zs, (_Float16*)nullptr);
        decoder_fallback<<<dim3(T_CURN, N_TREAT), 256, 0, stream>>>(
            cc, zs, dW1, db1, dW2, db2, preds);
    }
}